// Round 8
// baseline (426.675 us; speedup 1.0000x reference)
//
#include <hip/hip_runtime.h>

// Fused: bicubic 2x upsample -> leaky_relu(0.01) -> antialiased bicubic 2x down.
// NHWC f32, B=16, H=W=128, C=128.
// Round 8: horizontal pipeline in packed fp16 (v_pk_fma_f16 over the even/odd
// fine-row pair), fp16x2 LDS exchange (rowv 33KB -> 17KB), RS=8 / 2048 blocks
// (5 blocks/CU resident), v-up & v-down kept in f32.

typedef _Float16 h2 __attribute__((ext_vector_type(2)));

#define HH 128
#define WW 128
#define CC 128
#define RS 8        // output rows per strip
#define CH 16       // channels per block
#define PADH2 132   // LDS row stride in h2 elems (16B-aligned quads)
#define NSTEP (RS + 4)

// lgkm-only barrier: LDS visibility without draining global loads/stores.
#define LBAR() asm volatile("s_waitcnt lgkmcnt(0)\n\ts_barrier" ::: "memory")

__device__ __forceinline__ h2 H2(float v) {
  _Float16 h = (_Float16)v;
  return (h2){h, h};
}

__device__ __forceinline__ double keys_cubic(double x) {
  // JAX _fill_keys_cubic_kernel (a = -0.5)
  if (x >= 2.0) return 0.0;
  if (x >= 1.0) return ((-0.5 * x + 2.5) * x - 4.0) * x + 2.0;
  return (1.5 * x - 2.5) * x * x + 1.0;
}

__global__ __launch_bounds__(256, 5) void fused_updown_kernel(
    const float* __restrict__ x, float* __restrict__ out) {
  __shared__ __align__(16) float wUpV[256][4];     // fine row -> 4 taps (f32, v-up)
  __shared__ __align__(16) float wDnE[4][8];       // out row/col 0,1,126,127 -> 8 taps
  __shared__ __align__(16) h2 wUpH2[6][4];         // fine col 0,1,2,253,254,255 (splat)
  __shared__ __align__(16) h2 wDnH2[4][8];         // out col 0,1,126,127 (splat)
  __shared__ __align__(16) h2 rowv[2][CH][PADH2];  // packed (even,odd) fine rows, fp16

  const int tid = threadIdx.x;

  // ---- weight tables (renormalized truncation, matches jax.image.resize) ----
  {
    const int k = tid;
    const double q = 0.5 * k - 0.25;          // sample_f = (k+0.5)/2 - 0.5
    const int st = ((k + 1) >> 1) - 2;
    double wr[4], s = 0.0;
#pragma unroll
    for (int i = 0; i < 4; ++i) {
      const int col = st + i;
      double w = (col >= 0 && col <= 127) ? keys_cubic(fabs((double)col - q)) : 0.0;
      wr[i] = w; s += w;
    }
    const double inv = 1.0 / s;
#pragma unroll
    for (int i = 0; i < 4; ++i) wUpV[k][i] = (float)(wr[i] * inv);
  }
  if (tid < 4) {
    const int e = tid;
    const int j = (e < 2) ? e : 124 + e;      // 0,1,126,127
    const double p = 2.0 * j + 0.5;           // sample_f = (j+0.5)*2 - 0.5
    const int st = 2 * j - 3;
    double wr[8], s = 0.0;
#pragma unroll
    for (int i = 0; i < 8; ++i) {
      const int col = st + i;
      double w = (col >= 0 && col <= 255) ? keys_cubic(0.5 * fabs((double)col - p)) : 0.0;
      wr[i] = w; s += w;
    }
    const double inv = 1.0 / s;
#pragma unroll
    for (int i = 0; i < 8; ++i) wDnE[e][i] = (float)(wr[i] * inv);
  }
  __syncthreads();
  // fp16 splat copies of the boundary tables (ordered by the next barrier)
  if (tid < 6) {
    const int k = (tid < 3) ? tid : 250 + tid;   // 0,1,2,253,254,255
#pragma unroll
    for (int i = 0; i < 4; ++i) wUpH2[tid][i] = H2(wUpV[k][i]);
  }
  if (tid < 4) {
#pragma unroll
    for (int i = 0; i < 8; ++i) wDnH2[tid][i] = H2(wDnE[tid][i]);
  }

  const int bid = blockIdx.x;
  const int b = bid & 15;
  const int strip = (bid >> 4) & 15;
  const int chunk = bid >> 8;                  // 0..7
  const int oy0 = strip * RS;
  const int c0 = chunk * CH;
  const int c = tid & 15;                      // channel (lane-contiguous)
  const int g = tid >> 4;                      // col group 0..15
  const int col0 = g * 8;
  const bool gL = (g == 0), gR = (g == 15);

  const float* xbase = x + (size_t)b * (HH * WW * CC) + (size_t)col0 * CC + (c0 + c);
  float* obase = out + (size_t)b * (HH * WW * CC) + (size_t)col0 * CC + (c0 + c);
  const int m0 = oy0 - 2;

  auto load_row = [&](float (&d)[8], int row) {
    row = row < 0 ? 0 : (row > 127 ? 127 : row);
    const float* p = xbase + (size_t)row * (WW * CC);
#pragma unroll
    for (int j = 0; j < 8; ++j) d[j] = p[j * CC];
  };

  // vertical-downsample weight for output row oy at tap (interior const cst)
  auto wdGet = [&](int oy, float cst, int tap) -> float {
    if (oy < 0 || oy > 127) return 0.f;
    if (oy < 2) return wDnE[oy][tap];
    if (oy > 125) return wDnE[oy - 124][tap];
    return cst;
  };

  float r0[8], r1[8], r2[8], r3[8], r4[8], r5[8];
  float A0[8], A1[8], A2[8], A3[8], A4[8];
#pragma unroll
  for (int i = 0; i < 8; ++i) { A0[i]=0.f; A1[i]=0.f; A2[i]=0.f; A3[i]=0.f; A4[i]=0.f; }

  load_row(r0, m0 - 2);
  load_row(r1, m0 - 1);
  load_row(r2, m0);
  load_row(r3, m0 + 1);
  load_row(r4, m0 + 2);
  load_row(r5, m0 + 3);

  for (int t = 0; t < NSTEP; ++t) {
    const int m = m0 + t;
    if (t > 0) {
#pragma unroll
      for (int i = 0; i < 8; ++i) {
        r0[i]=r1[i]; r1[i]=r2[i]; r2[i]=r3[i]; r3[i]=r4[i]; r4[i]=r5[i];
      }
      load_row(r5, m + 3);                 // consumed next step (spans the LBAR)
    }
    const bool mOK = (m >= 0) && (m <= 127);
    const int sp = t & 1;
    __align__(16) h2 vh[8];                 // packed (even,odd) own fine cols
    if (mOK) {
      // vertical upsample in f32 (even row 2m | odd row 2m+1), then pack fp16
      float4 we, wo;
      if (m >= 2 && m <= 125) {
        we = make_float4(-0.0234375f, 0.2265625f, 0.8671875f, -0.0703125f);
        wo = make_float4(-0.0703125f, 0.8671875f, 0.2265625f, -0.0234375f);
      } else {
        we = *(const float4*)wUpV[2 * m];
        wo = *(const float4*)wUpV[2 * m + 1];
      }
#pragma unroll
      for (int j = 0; j < 8; ++j) {
        const float vE = (we.x * r0[j] + we.y * r1[j]) + (we.z * r2[j] + we.w * r3[j]);
        const float vO = (wo.x * r1[j] + wo.y * r2[j]) + (wo.z * r3[j] + wo.w * r4[j]);
        vh[j] = (h2){(_Float16)vE, (_Float16)vO};
      }
      *(float4*)&rowv[sp][c][col0]     = *(const float4*)&vh[0];
      *(float4*)&rowv[sp][c][col0 + 4] = *(const float4*)&vh[4];
    }
    LBAR();
    if (mOK) {
      // halo gather: packed fine-row pair at coarse cols col0-4 .. col0+11
      __align__(16) h2 vv[16];
      if (!gL) {
        *(float4*)&vv[0] = *(const float4*)&rowv[sp][c][col0 - 4];
      } else {
#pragma unroll
        for (int i = 0; i < 4; ++i) vv[i] = H2(0.f);
      }
#pragma unroll
      for (int j = 0; j < 8; ++j) vv[4 + j] = vh[j];
      if (!gR) {
        *(float4*)&vv[12] = *(const float4*)&rowv[sp][c][col0 + 8];
      } else {
#pragma unroll
        for (int i = 0; i < 4; ++i) vv[12 + i] = H2(0.f);
      }

      // horizontal upsample + leaky (packed fp16), fine cols k0..k0+21
      h2 ff[22];
#pragma unroll
      for (int u = 0; u < 22; ++u) {
        const int s = (u >> 1) + 1;
        h2 t2;
        if (u & 1)
          t2 = (vv[s] * H2(-0.0234375f) + vv[s + 1] * H2(0.2265625f))
             + (vv[s + 2] * H2(0.8671875f) + vv[s + 3] * H2(-0.0703125f));
        else
          t2 = (vv[s] * H2(-0.0703125f) + vv[s + 1] * H2(0.8671875f))
             + (vv[s + 2] * H2(0.2265625f) + vv[s + 3] * H2(-0.0234375f));
        ff[u] = __builtin_elementwise_max(t2, t2 * H2(0.01f));
      }
      if (gL) {              // fine cols 0,1,2 boundary weights (k0 = -3)
#pragma unroll
        for (int u = 3; u <= 5; ++u) {
          const int s = (u >> 1) + 1;
          h2 t2 = (vv[s] * wUpH2[u - 3][0] + vv[s + 1] * wUpH2[u - 3][1])
                + (vv[s + 2] * wUpH2[u - 3][2] + vv[s + 3] * wUpH2[u - 3][3]);
          ff[u] = __builtin_elementwise_max(t2, t2 * H2(0.01f));
        }
      }
      if (gR) {              // fine cols 253,254,255 (k0 = 237)
#pragma unroll
        for (int u = 16; u <= 18; ++u) {
          const int s = (u >> 1) + 1;
          h2 t2 = (vv[s] * wUpH2[u - 13][0] + vv[s + 1] * wUpH2[u - 13][1])
                + (vv[s + 2] * wUpH2[u - 13][2] + vv[s + 3] * wUpH2[u - 13][3]);
          ff[u] = __builtin_elementwise_max(t2, t2 * H2(0.01f));
        }
      }

      // horizontal downsample (packed fp16, interior symmetric 8-tap)
      h2 tt[8];
#pragma unroll
      for (int jj = 0; jj < 8; ++jj) {
        const h2 p0 = ff[2*jj]     + ff[2*jj + 7];
        const h2 p1 = ff[2*jj + 1] + ff[2*jj + 6];
        const h2 p2 = ff[2*jj + 2] + ff[2*jj + 5];
        const h2 p3 = ff[2*jj + 3] + ff[2*jj + 4];
        tt[jj] = (p0 * H2(-0.01171875f) + p1 * H2(-0.03515625f))
               + (p2 * H2(0.11328125f)  + p3 * H2(0.43359375f));
      }
      if (gL) {
#pragma unroll
        for (int jj = 0; jj < 2; ++jj) {
          h2 s2 = H2(0.f);
#pragma unroll
          for (int i = 0; i < 8; ++i) s2 += ff[2*jj + i] * wDnH2[jj][i];
          tt[jj] = s2;
        }
      }
      if (gR) {
#pragma unroll
        for (int jj = 6; jj < 8; ++jj) {
          h2 s2 = H2(0.f);
#pragma unroll
          for (int i = 0; i < 8; ++i) s2 += ff[2*jj + i] * wDnH2[jj - 4][i];
          tt[jj] = s2;
        }
      }

      // vertical-downsample scatter in f32
      const float wE0 = wdGet(m - 2, -0.01171875f, 7);
      const float wE1 = wdGet(m - 1, 0.11328125f, 5);
      const float wE2 = wdGet(m, 0.43359375f, 3);
      const float wE3 = wdGet(m + 1, -0.03515625f, 1);
      const float wO0 = wdGet(m - 1, -0.03515625f, 6);
      const float wO1 = wdGet(m, 0.43359375f, 4);
      const float wO2 = wdGet(m + 1, 0.11328125f, 2);
      const float wO3 = wdGet(m + 2, -0.01171875f, 0);
#pragma unroll
      for (int jj = 0; jj < 8; ++jj) {
        const float te = (float)tt[jj].x, to = (float)tt[jj].y;
        A0[jj] = fmaf(wE0, te, A0[jj]);
        A1[jj] = fmaf(wE1, te, fmaf(wO0, to, A1[jj]));
        A2[jj] = fmaf(wE2, te, fmaf(wO1, to, A2[jj]));
        A3[jj] = fmaf(wE3, te, fmaf(wO2, to, A3[jj]));
        A4[jj] = fmaf(wO3, to, A4[jj]);
      }
    }
    if (m - 2 >= oy0) {
      float* op = obase + (size_t)(m - 2) * (WW * CC);
#pragma unroll
      for (int jj = 0; jj < 8; ++jj) op[jj * CC] = A0[jj];
    }
#pragma unroll
    for (int jj = 0; jj < 8; ++jj) {
      A0[jj]=A1[jj]; A1[jj]=A2[jj]; A2[jj]=A3[jj]; A3[jj]=A4[jj]; A4[jj]=0.f;
    }
  }
}

extern "C" void kernel_launch(void* const* d_in, const int* in_sizes, int n_in,
                              void* d_out, int out_size, void* d_ws, size_t ws_size,
                              hipStream_t stream) {
  const float* x = (const float*)d_in[0];
  float* o = (float*)d_out;
  dim3 grid(16 * 16 * 8);   // batch(16) x strips(16) x channel-chunks(8)
  dim3 block(256);
  hipLaunchKernelGGL(fused_updown_kernel, grid, block, 0, stream, x, o);
}

// Round 9
// 96.029 us; speedup vs baseline: 4.4432x; 4.4432x over previous
//
#include <hip/hip_runtime.h>

// Fused: bicubic 2x upsample -> leaky_relu(0.01) -> antialiased bicubic 2x down.
// NHWC f32, B=16, H=W=128, C=128.
// Round 9 = round 8 (packed-fp16 horizontal pipeline, fp16x2 LDS exchange,
// lgkm-only barriers) with the spill-inducing knobs reverted:
//   - plain __launch_bounds__(256)  (r8's min-waves=5 forced VGPR->48 + spill)
//   - RS=16, grid 1024 (r8's RS=8 doubled halo work)
// v-up and v-down stay f32; only the horizontal pipeline is fp16.

typedef _Float16 h2 __attribute__((ext_vector_type(2)));

#define HH 128
#define WW 128
#define CC 128
#define RS 16       // output rows per strip
#define CH 16       // channels per block
#define PADH2 132   // LDS row stride in h2 elems (16B-aligned quads)
#define NSTEP (RS + 4)

// lgkm-only barrier: LDS visibility without draining global loads/stores.
#define LBAR() asm volatile("s_waitcnt lgkmcnt(0)\n\ts_barrier" ::: "memory")

__device__ __forceinline__ h2 H2(float v) {
  _Float16 h = (_Float16)v;
  return (h2){h, h};
}

__device__ __forceinline__ double keys_cubic(double x) {
  // JAX _fill_keys_cubic_kernel (a = -0.5)
  if (x >= 2.0) return 0.0;
  if (x >= 1.0) return ((-0.5 * x + 2.5) * x - 4.0) * x + 2.0;
  return (1.5 * x - 2.5) * x * x + 1.0;
}

__global__ __launch_bounds__(256) void fused_updown_kernel(
    const float* __restrict__ x, float* __restrict__ out) {
  __shared__ __align__(16) float wUpV[256][4];     // fine row -> 4 taps (f32, v-up)
  __shared__ __align__(16) float wDnE[4][8];       // out row/col 0,1,126,127 -> 8 taps
  __shared__ __align__(16) h2 wUpH2[6][4];         // fine col 0,1,2,253,254,255 (splat)
  __shared__ __align__(16) h2 wDnH2[4][8];         // out col 0,1,126,127 (splat)
  __shared__ __align__(16) h2 rowv[2][CH][PADH2];  // packed (even,odd) fine rows, fp16

  const int tid = threadIdx.x;

  // ---- weight tables (renormalized truncation, matches jax.image.resize) ----
  {
    const int k = tid;
    const double q = 0.5 * k - 0.25;          // sample_f = (k+0.5)/2 - 0.5
    const int st = ((k + 1) >> 1) - 2;
    double wr[4], s = 0.0;
#pragma unroll
    for (int i = 0; i < 4; ++i) {
      const int col = st + i;
      double w = (col >= 0 && col <= 127) ? keys_cubic(fabs((double)col - q)) : 0.0;
      wr[i] = w; s += w;
    }
    const double inv = 1.0 / s;
#pragma unroll
    for (int i = 0; i < 4; ++i) wUpV[k][i] = (float)(wr[i] * inv);
  }
  if (tid < 4) {
    const int e = tid;
    const int j = (e < 2) ? e : 124 + e;      // 0,1,126,127
    const double p = 2.0 * j + 0.5;           // sample_f = (j+0.5)*2 - 0.5
    const int st = 2 * j - 3;
    double wr[8], s = 0.0;
#pragma unroll
    for (int i = 0; i < 8; ++i) {
      const int col = st + i;
      double w = (col >= 0 && col <= 255) ? keys_cubic(0.5 * fabs((double)col - p)) : 0.0;
      wr[i] = w; s += w;
    }
    const double inv = 1.0 / s;
#pragma unroll
    for (int i = 0; i < 8; ++i) wDnE[e][i] = (float)(wr[i] * inv);
  }
  __syncthreads();
  // fp16 splat copies of the boundary tables (visible after the loop's first LBAR)
  if (tid < 6) {
    const int k = (tid < 3) ? tid : 250 + tid;   // 0,1,2,253,254,255
#pragma unroll
    for (int i = 0; i < 4; ++i) wUpH2[tid][i] = H2(wUpV[k][i]);
  }
  if (tid < 4) {
#pragma unroll
    for (int i = 0; i < 8; ++i) wDnH2[tid][i] = H2(wDnE[tid][i]);
  }

  const int bid = blockIdx.x;
  const int b = bid & 15;
  const int strip = (bid >> 4) & 7;
  const int chunk = bid >> 7;                  // 0..7
  const int oy0 = strip * RS;
  const int c0 = chunk * CH;
  const int c = tid & 15;                      // channel (lane-contiguous)
  const int g = tid >> 4;                      // col group 0..15
  const int col0 = g * 8;
  const bool gL = (g == 0), gR = (g == 15);

  const float* xbase = x + (size_t)b * (HH * WW * CC) + (size_t)col0 * CC + (c0 + c);
  float* obase = out + (size_t)b * (HH * WW * CC) + (size_t)col0 * CC + (c0 + c);
  const int m0 = oy0 - 2;

  auto load_row = [&](float (&d)[8], int row) {
    row = row < 0 ? 0 : (row > 127 ? 127 : row);
    const float* p = xbase + (size_t)row * (WW * CC);
#pragma unroll
    for (int j = 0; j < 8; ++j) d[j] = p[j * CC];
  };

  // vertical-downsample weight for output row oy at tap (interior const cst)
  auto wdGet = [&](int oy, float cst, int tap) -> float {
    if (oy < 0 || oy > 127) return 0.f;
    if (oy < 2) return wDnE[oy][tap];
    if (oy > 125) return wDnE[oy - 124][tap];
    return cst;
  };

  float r0[8], r1[8], r2[8], r3[8], r4[8], r5[8];
  float A0[8], A1[8], A2[8], A3[8], A4[8];
#pragma unroll
  for (int i = 0; i < 8; ++i) { A0[i]=0.f; A1[i]=0.f; A2[i]=0.f; A3[i]=0.f; A4[i]=0.f; }

  load_row(r0, m0 - 2);
  load_row(r1, m0 - 1);
  load_row(r2, m0);
  load_row(r3, m0 + 1);
  load_row(r4, m0 + 2);
  load_row(r5, m0 + 3);

  for (int t = 0; t < NSTEP; ++t) {
    const int m = m0 + t;
    if (t > 0) {
#pragma unroll
      for (int i = 0; i < 8; ++i) {
        r0[i]=r1[i]; r1[i]=r2[i]; r2[i]=r3[i]; r3[i]=r4[i]; r4[i]=r5[i];
      }
      load_row(r5, m + 3);                 // consumed next step (spans the LBAR)
    }
    const bool mOK = (m >= 0) && (m <= 127);
    const int sp = t & 1;
    __align__(16) h2 vh[8];                 // packed (even,odd) own fine cols
    if (mOK) {
      // vertical upsample in f32 (even row 2m | odd row 2m+1), then pack fp16
      float4 we, wo;
      if (m >= 2 && m <= 125) {
        we = make_float4(-0.0234375f, 0.2265625f, 0.8671875f, -0.0703125f);
        wo = make_float4(-0.0703125f, 0.8671875f, 0.2265625f, -0.0234375f);
      } else {
        we = *(const float4*)wUpV[2 * m];
        wo = *(const float4*)wUpV[2 * m + 1];
      }
#pragma unroll
      for (int j = 0; j < 8; ++j) {
        const float vE = (we.x * r0[j] + we.y * r1[j]) + (we.z * r2[j] + we.w * r3[j]);
        const float vO = (wo.x * r1[j] + wo.y * r2[j]) + (wo.z * r3[j] + wo.w * r4[j]);
        vh[j] = (h2){(_Float16)vE, (_Float16)vO};
      }
      *(float4*)&rowv[sp][c][col0]     = *(const float4*)&vh[0];
      *(float4*)&rowv[sp][c][col0 + 4] = *(const float4*)&vh[4];
    }
    LBAR();
    if (mOK) {
      // halo gather: packed fine-row pair at coarse cols col0-4 .. col0+11
      __align__(16) h2 vv[16];
      if (!gL) {
        *(float4*)&vv[0] = *(const float4*)&rowv[sp][c][col0 - 4];
      } else {
#pragma unroll
        for (int i = 0; i < 4; ++i) vv[i] = H2(0.f);
      }
#pragma unroll
      for (int j = 0; j < 8; ++j) vv[4 + j] = vh[j];
      if (!gR) {
        *(float4*)&vv[12] = *(const float4*)&rowv[sp][c][col0 + 8];
      } else {
#pragma unroll
        for (int i = 0; i < 4; ++i) vv[12 + i] = H2(0.f);
      }

      // horizontal upsample + leaky (packed fp16), fine cols k0..k0+21
      h2 ff[22];
#pragma unroll
      for (int u = 0; u < 22; ++u) {
        const int s = (u >> 1) + 1;
        h2 t2;
        if (u & 1)
          t2 = (vv[s] * H2(-0.0234375f) + vv[s + 1] * H2(0.2265625f))
             + (vv[s + 2] * H2(0.8671875f) + vv[s + 3] * H2(-0.0703125f));
        else
          t2 = (vv[s] * H2(-0.0703125f) + vv[s + 1] * H2(0.8671875f))
             + (vv[s + 2] * H2(0.2265625f) + vv[s + 3] * H2(-0.0234375f));
        ff[u] = __builtin_elementwise_max(t2, t2 * H2(0.01f));
      }
      if (gL) {              // fine cols 0,1,2 boundary weights (k0 = -3)
#pragma unroll
        for (int u = 3; u <= 5; ++u) {
          const int s = (u >> 1) + 1;
          h2 t2 = (vv[s] * wUpH2[u - 3][0] + vv[s + 1] * wUpH2[u - 3][1])
                + (vv[s + 2] * wUpH2[u - 3][2] + vv[s + 3] * wUpH2[u - 3][3]);
          ff[u] = __builtin_elementwise_max(t2, t2 * H2(0.01f));
        }
      }
      if (gR) {              // fine cols 253,254,255 (k0 = 237)
#pragma unroll
        for (int u = 16; u <= 18; ++u) {
          const int s = (u >> 1) + 1;
          h2 t2 = (vv[s] * wUpH2[u - 13][0] + vv[s + 1] * wUpH2[u - 13][1])
                + (vv[s + 2] * wUpH2[u - 13][2] + vv[s + 3] * wUpH2[u - 13][3]);
          ff[u] = __builtin_elementwise_max(t2, t2 * H2(0.01f));
        }
      }

      // horizontal downsample (packed fp16, interior symmetric 8-tap)
      h2 tt[8];
#pragma unroll
      for (int jj = 0; jj < 8; ++jj) {
        const h2 p0 = ff[2*jj]     + ff[2*jj + 7];
        const h2 p1 = ff[2*jj + 1] + ff[2*jj + 6];
        const h2 p2 = ff[2*jj + 2] + ff[2*jj + 5];
        const h2 p3 = ff[2*jj + 3] + ff[2*jj + 4];
        tt[jj] = (p0 * H2(-0.01171875f) + p1 * H2(-0.03515625f))
               + (p2 * H2(0.11328125f)  + p3 * H2(0.43359375f));
      }
      if (gL) {
#pragma unroll
        for (int jj = 0; jj < 2; ++jj) {
          h2 s2 = H2(0.f);
#pragma unroll
          for (int i = 0; i < 8; ++i) s2 += ff[2*jj + i] * wDnH2[jj][i];
          tt[jj] = s2;
        }
      }
      if (gR) {
#pragma unroll
        for (int jj = 6; jj < 8; ++jj) {
          h2 s2 = H2(0.f);
#pragma unroll
          for (int i = 0; i < 8; ++i) s2 += ff[2*jj + i] * wDnH2[jj - 4][i];
          tt[jj] = s2;
        }
      }

      // vertical-downsample scatter in f32
      const float wE0 = wdGet(m - 2, -0.01171875f, 7);
      const float wE1 = wdGet(m - 1, 0.11328125f, 5);
      const float wE2 = wdGet(m, 0.43359375f, 3);
      const float wE3 = wdGet(m + 1, -0.03515625f, 1);
      const float wO0 = wdGet(m - 1, -0.03515625f, 6);
      const float wO1 = wdGet(m, 0.43359375f, 4);
      const float wO2 = wdGet(m + 1, 0.11328125f, 2);
      const float wO3 = wdGet(m + 2, -0.01171875f, 0);
#pragma unroll
      for (int jj = 0; jj < 8; ++jj) {
        const float te = (float)tt[jj].x, to = (float)tt[jj].y;
        A0[jj] = fmaf(wE0, te, A0[jj]);
        A1[jj] = fmaf(wE1, te, fmaf(wO0, to, A1[jj]));
        A2[jj] = fmaf(wE2, te, fmaf(wO1, to, A2[jj]));
        A3[jj] = fmaf(wE3, te, fmaf(wO2, to, A3[jj]));
        A4[jj] = fmaf(wO3, to, A4[jj]);
      }
    }
    if (m - 2 >= oy0) {
      float* op = obase + (size_t)(m - 2) * (WW * CC);
#pragma unroll
      for (int jj = 0; jj < 8; ++jj) op[jj * CC] = A0[jj];
    }
#pragma unroll
    for (int jj = 0; jj < 8; ++jj) {
      A0[jj]=A1[jj]; A1[jj]=A2[jj]; A2[jj]=A3[jj]; A3[jj]=A4[jj]; A4[jj]=0.f;
    }
  }
}

extern "C" void kernel_launch(void* const* d_in, const int* in_sizes, int n_in,
                              void* d_out, int out_size, void* d_ws, size_t ws_size,
                              hipStream_t stream) {
  const float* x = (const float*)d_in[0];
  float* o = (float*)d_out;
  dim3 grid(16 * 8 * 8);   // batch(16) x strips(8) x channel-chunks(8)
  dim3 block(256);
  hipLaunchKernelGGL(fused_updown_kernel, grid, block, 0, stream, x, o);
}